// Round 1
// baseline (235.380 us; speedup 1.0000x reference)
//
#include <hip/hip_runtime.h>

#define EPSB 1e-5f

typedef __bf16 bf16x8 __attribute__((ext_vector_type(8)));
typedef float f32x4 __attribute__((ext_vector_type(4)));

__device__ __forceinline__ unsigned short f2bf(float f) {
  union { float f; unsigned int u; } v; v.f = f;
  unsigned int r = v.u + 0x7FFFu + ((v.u >> 16) & 1u);
  return (unsigned short)(r >> 16);
}
__device__ __forceinline__ float bf2f(unsigned short u) {
  union { unsigned int u; float f; } v; v.u = ((unsigned int)u) << 16;
  return v.f;
}

// ---------------- prep: fold BN into bf16 weights ----------------
// wAe: [576][160] bf16, k = c*49+ki*7+kj (k<147), k==147 holds folded bias, rest 0
// w1e: [64][576]  bf16 (k = c9, matches unfold layout c*9+kk)
// w2e: [64][576]  bf16 reordered kk-major: [o][kk*64 + c]
__global__ void prep_kernel(
    const float* __restrict__ w_att, const float* __restrict__ b_att,
    const float* __restrict__ gA, const float* __restrict__ beA,
    const float* __restrict__ mA, const float* __restrict__ vA,
    const float* __restrict__ w1, const float* __restrict__ b1,
    const float* __restrict__ g1, const float* __restrict__ be1,
    const float* __restrict__ m1, const float* __restrict__ v1,
    const float* __restrict__ w2, const float* __restrict__ b2,
    const float* __restrict__ g2, const float* __restrict__ be2,
    const float* __restrict__ m2, const float* __restrict__ v2,
    unsigned short* __restrict__ wAe, unsigned short* __restrict__ w1e,
    unsigned short* __restrict__ w2e, float* __restrict__ bias1,
    float* __restrict__ bias2)
{
  int i = blockIdx.x * 256 + threadIdx.x;
  if (i < 576 * 160) {
    int o = i / 160, k = i - o * 160;
    float s = gA[o] * rsqrtf(vA[o] + EPSB);
    float v = 0.f;
    if (k < 147) {
      int c = k / 49, rem = k - c * 49, ki = rem / 7, kj = rem - ki * 7;
      v = w_att[(o * 3 + c) * 49 + ki * 7 + kj] * s;
    } else if (k == 147) {
      v = b_att[o] * s + beA[o] - mA[o] * s;
    }
    wAe[i] = f2bf(v);
    return;
  }
  i -= 576 * 160;
  if (i < 64 * 576) {
    int o = i / 576;
    float s = g1[o] * rsqrtf(v1[o] + EPSB);
    w1e[i] = f2bf(w1[i] * s);
    return;
  }
  i -= 64 * 576;
  if (i < 64 * 576) {
    int o = i / 576, r = i - o * 576, kk = r >> 6, c = r & 63;
    float s = g2[o] * rsqrtf(v2[o] + EPSB);
    w2e[i] = f2bf(w2[(o * 64 + c) * 9 + kk] * s);
    return;
  }
  i -= 64 * 576;
  if (i < 64) {
    float s = g1[i] * rsqrtf(v1[i] + EPSB);
    bias1[i] = b1[i] * s + be1[i] - m1[i] * s;
  } else if (i < 128) {
    int o = i - 64;
    float s = g2[o] * rsqrtf(v2[o] + EPSB);
    bias2[o] = b2[o] * s + be2[o] - m2[o] * s;
  }
}

// ---------------- K12: attention GEMM + sigmoid gate + 1x1 conv ----------------
// One block = 64 pixels of one row (n, y, x0..x0+63); 4 waves.
// GEMM1: M=576 (9 chunks of 64), K=160 ; GEMM2: M=64, K=576 (chunked with GEMM1)
// h1 out: [n][y][x][c] bf16
__global__ __launch_bounds__(256) void k12_kernel(
    const float* __restrict__ new_xyz, const float* __restrict__ feature,
    const unsigned short* __restrict__ wAe, const unsigned short* __restrict__ w1e,
    const float* __restrict__ bias1, unsigned short* __restrict__ h1g)
{
  __shared__ float          s_xyz[3][7][72];           // new_xyz tile (rows y-3..y+3, x0-3..x0+66)
  __shared__ unsigned short s_B1[64][168];             // im2col [pixel][k], stride 336B
  __shared__ unsigned short s_feat[3][66][64];         // feature tile, c swizzled by (c+xx)&63
  __shared__ unsigned short s_B2[64][72];              // gated chunk [pixel][kloc], stride 144B

  const int x0 = blockIdx.x * 64;
  const int y  = blockIdx.y;
  const int n  = blockIdx.z;
  const int tid = threadIdx.x;
  const int lane = tid & 63;
  const int wv = tid >> 6;
  const int r16 = lane & 15;
  const int kq = lane >> 4;

  // stage new_xyz tile (zero-padded halo)
  for (int idx = tid; idx < 3 * 7 * 70; idx += 256) {
    int c = idx / 490, rem = idx - c * 490, r = rem / 70, xx = rem - r * 70;
    int yy = y + r - 3, xg = x0 + xx - 3;
    float v = 0.f;
    if (yy >= 0 && yy < 64 && xg >= 0 && xg < 512)
      v = new_xyz[((n * 3 + c) * 64 + yy) * 512 + xg];
    s_xyz[c][r][xx] = v;
  }
  // stage feature tile (rows y-1..y+1, x0-1..x0+64), bf16, bank-swizzled
  for (int idx = tid; idx < 64 * 198; idx += 256) {
    int c = idx / 198, rem = idx - c * 198, r = rem / 66, xx = rem - r * 66;
    int yy = y + r - 1, xg = x0 + xx - 1;
    float v = 0.f;
    if (yy >= 0 && yy < 64 && xg >= 0 && xg < 512)
      v = feature[((n * 64 + c) * 64 + yy) * 512 + xg];
    s_feat[r][xx][(c + xx) & 63] = f2bf(v);
  }
  __syncthreads();
  // build im2col B1 [p][k]; k=147 -> 1.0 (bias slot), 148..159 -> 0
  for (int idx = tid; idx < 64 * 160; idx += 256) {
    int p = idx / 160, k = idx - p * 160;
    float v = 0.f;
    if (k < 147) {
      int c = k / 49, rem = k - c * 49, ki = rem / 7, kj = rem - ki * 7;
      v = s_xyz[c][ki][p + kj];
    } else if (k == 147) {
      v = 1.0f;
    }
    s_B1[p][k] = f2bf(v);
  }
  __syncthreads();

  f32x4 acc2[4];
#pragma unroll
  for (int i = 0; i < 4; ++i) acc2[i] = {0.f, 0.f, 0.f, 0.f};

  for (int m0 = 0; m0 < 576; m0 += 64) {
    // ---- GEMM1 chunk: rows m0+16*wv .. +16, 64 pixels ----
    f32x4 acc1[4];
#pragma unroll
    for (int i = 0; i < 4; ++i) acc1[i] = {0.f, 0.f, 0.f, 0.f};
    const unsigned short* Ap = wAe + (m0 + 16 * wv + r16) * 160 + kq * 8;
#pragma unroll
    for (int kst = 0; kst < 5; ++kst) {
      bf16x8 a = *(const bf16x8*)(Ap + kst * 32);
#pragma unroll
      for (int pf = 0; pf < 4; ++pf) {
        bf16x8 b = *(const bf16x8*)(&s_B1[pf * 16 + r16][kst * 32 + kq * 8]);
        acc1[pf] = __builtin_amdgcn_mfma_f32_16x16x32_bf16(a, b, acc1[pf], 0, 0, 0);
      }
    }
    // ---- sigmoid gate + write B2 chunk ----
#pragma unroll
    for (int pf = 0; pf < 4; ++pf) {
      int p = pf * 16 + r16;
#pragma unroll
      for (int rp = 0; rp < 2; ++rp) {
        unsigned int packed = 0;
#pragma unroll
        for (int rb = 0; rb < 2; ++rb) {
          int r = rp * 2 + rb;
          int c9 = m0 + 16 * wv + kq * 4 + r;
          float att = 1.f / (1.f + __expf(-acc1[pf][r]));
          int cc = c9 / 9;
          int kk = c9 - cc * 9;
          int di = kk / 3, dj = kk - di * 3;
          int xxp = p + dj;
          float fv = bf2f(s_feat[di][xxp][(cc + xxp) & 63]);
          packed |= ((unsigned int)f2bf(att * fv)) << (16 * rb);
        }
        *(unsigned int*)&s_B2[p][16 * wv + kq * 4 + rp * 2] = packed;
      }
    }
    __syncthreads();
    // ---- GEMM2 partial over this 64-k slice ----
    const unsigned short* A2p = w1e + (16 * wv + r16) * 576 + m0 + kq * 8;
#pragma unroll
    for (int kst = 0; kst < 2; ++kst) {
      bf16x8 a = *(const bf16x8*)(A2p + kst * 32);
#pragma unroll
      for (int pf = 0; pf < 4; ++pf) {
        bf16x8 b = *(const bf16x8*)(&s_B2[pf * 16 + r16][kst * 32 + kq * 8]);
        acc2[pf] = __builtin_amdgcn_mfma_f32_16x16x32_bf16(a, b, acc2[pf], 0, 0, 0);
      }
    }
    __syncthreads();
  }

  // epilogue: h1 = relu(acc2 + bias1) -> bf16, transpose via LDS, coalesced store
#pragma unroll
  for (int pf = 0; pf < 4; ++pf) {
    int p = pf * 16 + r16;
#pragma unroll
    for (int rp = 0; rp < 2; ++rp) {
      unsigned int packed = 0;
#pragma unroll
      for (int rb = 0; rb < 2; ++rb) {
        int r = rp * 2 + rb;
        int ch = 16 * wv + kq * 4 + r;
        float v = fmaxf(acc2[pf][r] + bias1[ch], 0.f);
        packed |= ((unsigned int)f2bf(v)) << (16 * rb);
      }
      *(unsigned int*)&s_B2[p][16 * wv + kq * 4 + rp * 2] = packed;
    }
  }
  __syncthreads();
  unsigned short* dst = h1g + (((n * 64 + y) * 512) + x0) * 64;
  for (int idx = tid; idx < 1024; idx += 256) {
    int p = idx >> 4, c0 = (idx & 15) << 2;
    *(uint2*)(dst + p * 64 + c0) = *(const uint2*)(&s_B2[p][c0]);
  }
}

// ---------------- K3: 3x3 conv 64->64 + BN + ReLU + residual ----------------
__global__ __launch_bounds__(256) void k3_kernel(
    const unsigned short* __restrict__ h1g, const float* __restrict__ feature,
    const unsigned short* __restrict__ w2e, const float* __restrict__ bias2,
    float* __restrict__ out)
{
  __shared__ unsigned short s_h1[3][66][72];  // [row][xx][c], stride 144B

  const int x0 = blockIdx.x * 64;
  const int y  = blockIdx.y;
  const int n  = blockIdx.z;
  const int tid = threadIdx.x;
  const int lane = tid & 63;
  const int wv = tid >> 6;
  const int r16 = lane & 15;
  const int kq = lane >> 4;

  for (int idx = tid; idx < 3 * 66 * 16; idx += 256) {
    int r = idx / (66 * 16), rem = idx - r * 66 * 16, xx = rem >> 4, c0 = (rem & 15) << 2;
    int yy = y + r - 1, xg = x0 + xx - 1;
    uint2 v; v.x = 0u; v.y = 0u;
    if (yy >= 0 && yy < 64 && xg >= 0 && xg < 512)
      v = *(const uint2*)(h1g + (((n * 64 + yy) * 512) + xg) * 64 + c0);
    *(uint2*)(&s_h1[r][xx][c0]) = v;
  }
  __syncthreads();

  f32x4 acc[4];
#pragma unroll
  for (int i = 0; i < 4; ++i) acc[i] = {0.f, 0.f, 0.f, 0.f};

  const unsigned short* Ap = w2e + (16 * wv + r16) * 576 + kq * 8;
#pragma unroll 2
  for (int kst = 0; kst < 18; ++kst) {
    bf16x8 a = *(const bf16x8*)(Ap + kst * 32);
    int kk = kst >> 1, di = kk / 3, dj = kk - di * 3;
    int chalf = (kst & 1) << 5;
#pragma unroll
    for (int pf = 0; pf < 4; ++pf) {
      bf16x8 b = *(const bf16x8*)(&s_h1[di][pf * 16 + r16 + dj][chalf + kq * 8]);
      acc[pf] = __builtin_amdgcn_mfma_f32_16x16x32_bf16(a, b, acc[pf], 0, 0, 0);
    }
  }

#pragma unroll
  for (int pf = 0; pf < 4; ++pf) {
    int p = pf * 16 + r16;
#pragma unroll
    for (int r = 0; r < 4; ++r) {
      int ch = 16 * wv + kq * 4 + r;
      int off = (((n * 64 + ch) * 64) + y) * 512 + x0 + p;
      out[off] = fmaxf(acc[pf][r] + bias2[ch], 0.f) + feature[off];
    }
  }
}

// ---------------- launch ----------------
extern "C" void kernel_launch(void* const* d_in, const int* in_sizes, int n_in,
                              void* d_out, int out_size, void* d_ws, size_t ws_size,
                              hipStream_t stream)
{
  const float* new_xyz = (const float*)d_in[1];
  const float* feature = (const float*)d_in[2];
  const float* w_att = (const float*)d_in[3];
  const float* b_att = (const float*)d_in[4];
  const float* gA  = (const float*)d_in[5];
  const float* beA = (const float*)d_in[6];
  const float* mA  = (const float*)d_in[7];
  const float* vA  = (const float*)d_in[8];
  const float* w1  = (const float*)d_in[9];
  const float* b1  = (const float*)d_in[10];
  const float* g1  = (const float*)d_in[11];
  const float* be1 = (const float*)d_in[12];
  const float* m1  = (const float*)d_in[13];
  const float* v1  = (const float*)d_in[14];
  const float* w2  = (const float*)d_in[15];
  const float* b2  = (const float*)d_in[16];
  const float* g2  = (const float*)d_in[17];
  const float* be2 = (const float*)d_in[18];
  const float* m2  = (const float*)d_in[19];
  const float* v2  = (const float*)d_in[20];

  char* ws = (char*)d_ws;
  unsigned short* wAe = (unsigned short*)(ws);             // 576*160*2 = 184320
  unsigned short* w1e = (unsigned short*)(ws + 184320);    // 64*576*2  =  73728
  unsigned short* w2e = (unsigned short*)(ws + 258048);    // 64*576*2  =  73728
  float* bias1 = (float*)(ws + 331776);                    // 256
  float* bias2 = (float*)(ws + 332032);                    // 256
  unsigned short* h1g = (unsigned short*)(ws + 335872);    // 4*64*512*64*2 = 16777216

  prep_kernel<<<649, 256, 0, stream>>>(w_att, b_att, gA, beA, mA, vA,
                                       w1, b1, g1, be1, m1, v1,
                                       w2, b2, g2, be2, m2, v2,
                                       wAe, w1e, w2e, bias1, bias2);
  k12_kernel<<<dim3(8, 64, 4), 256, 0, stream>>>(new_xyz, feature, wAe, w1e, bias1, h1g);
  k3_kernel<<<dim3(8, 64, 4), 256, 0, stream>>>(h1g, feature, w2e, bias2, (float*)d_out);
}

// Round 2
// 183.835 us; speedup vs baseline: 1.2804x; 1.2804x over previous
//
#include <hip/hip_runtime.h>

#define EPSB 1e-5f

typedef __bf16 bf16x8 __attribute__((ext_vector_type(8)));
typedef float f32x4 __attribute__((ext_vector_type(4)));

__device__ __forceinline__ unsigned short f2bf(float f) {
  union { float f; unsigned int u; } v; v.f = f;
  unsigned int r = v.u + 0x7FFFu + ((v.u >> 16) & 1u);
  return (unsigned short)(r >> 16);
}
__device__ __forceinline__ float bf2f(unsigned short u) {
  union { unsigned int u; float f; } v; v.u = ((unsigned int)u) << 16;
  return v.f;
}
__device__ __forceinline__ float sigm(float x) {
  // sigmoid via native exp2 + rcp
  float e = __builtin_amdgcn_exp2f(-x * 1.4426950408889634f);
  return __builtin_amdgcn_rcpf(1.0f + e);
}

// ---------------- prep: fold BN into bf16 weights ----------------
// wAe: [576][160] bf16, PERMUTED rows: row' = kk*64+cc  <->  orig channel o = cc*9+kk
//      k = c*49+ki*7+kj (k<147), k==147 holds folded bias, rest 0
// w1e: [64][576]  bf16, k PERMUTED: k' = kk*64+cc  <->  orig k = cc*9+kk
// w2e: [64][576]  bf16 reordered kk-major: [o][kk*64 + c]
__global__ void prep_kernel(
    const float* __restrict__ w_att, const float* __restrict__ b_att,
    const float* __restrict__ gA, const float* __restrict__ beA,
    const float* __restrict__ mA, const float* __restrict__ vA,
    const float* __restrict__ w1, const float* __restrict__ b1,
    const float* __restrict__ g1, const float* __restrict__ be1,
    const float* __restrict__ m1, const float* __restrict__ v1,
    const float* __restrict__ w2, const float* __restrict__ b2,
    const float* __restrict__ g2, const float* __restrict__ be2,
    const float* __restrict__ m2, const float* __restrict__ v2,
    unsigned short* __restrict__ wAe, unsigned short* __restrict__ w1e,
    unsigned short* __restrict__ w2e, float* __restrict__ bias1,
    float* __restrict__ bias2)
{
  int i = blockIdx.x * 256 + threadIdx.x;
  if (i < 576 * 160) {
    int rp = i / 160, k = i - rp * 160;
    int kk = rp >> 6, cc = rp & 63;
    int o = cc * 9 + kk;
    float s = gA[o] * rsqrtf(vA[o] + EPSB);
    float v = 0.f;
    if (k < 147) {
      int c = k / 49, rem = k - c * 49, ki = rem / 7, kj = rem - ki * 7;
      v = w_att[(o * 3 + c) * 49 + ki * 7 + kj] * s;
    } else if (k == 147) {
      v = b_att[o] * s + beA[o] - mA[o] * s;
    }
    wAe[i] = f2bf(v);
    return;
  }
  i -= 576 * 160;
  if (i < 64 * 576) {
    int o = i / 576, kp = i - o * 576;
    int kk = kp >> 6, cc = kp & 63;
    float s = g1[o] * rsqrtf(v1[o] + EPSB);
    w1e[i] = f2bf(w1[o * 576 + cc * 9 + kk] * s);
    return;
  }
  i -= 64 * 576;
  if (i < 64 * 576) {
    int o = i / 576, r = i - o * 576, kk = r >> 6, c = r & 63;
    float s = g2[o] * rsqrtf(v2[o] + EPSB);
    w2e[i] = f2bf(w2[(o * 64 + c) * 9 + kk] * s);
    return;
  }
  i -= 64 * 576;
  if (i < 64) {
    float s = g1[i] * rsqrtf(v1[i] + EPSB);
    bias1[i] = b1[i] * s + be1[i] - m1[i] * s;
  } else if (i < 128) {
    int o = i - 64;
    float s = g2[o] * rsqrtf(v2[o] + EPSB);
    bias2[o] = b2[o] * s + be2[o] - m2[o] * s;
  }
}

// ---------------- K12: attention GEMM + sigmoid gate + 1x1 conv ----------------
// One block = 64 pixels of one row (n, y, x0..x0+63); 8 waves (512 thr).
// Wave = (wrow = wv&3 -> 16 channel rows, wcol = wv>>2 -> 32-px half).
// Chunks kk = 0..8 (kk-major permuted channels): per chunk fixed (di,dj).
__global__ __launch_bounds__(512, 4) void k12_kernel(
    const float* __restrict__ new_xyz, const float* __restrict__ feature,
    const unsigned short* __restrict__ wAe, const unsigned short* __restrict__ w1e,
    const float* __restrict__ bias1, unsigned short* __restrict__ h1g)
{
  // LDS layout (65280 B total):
  //  B1   [64][168] bf16  @ 0      (21504 B)  im2col, bank-balanced b128 reads
  //  feat [3][66][64] bf16 @ 21504 (25344 B)  swizzle ch -> (c+4*xx)&63
  //  B2   [2][64][72] bf16 @ 46848 (18432 B)  double-buffered gated chunk
  //  xyzb [23][136] bf16  (alias B2 buf0)     rows 0..20 xyz, 21=zeros, 22=ones
  //  lut  [160] int       (alias B2 buf0 +6256)
  __shared__ __align__(16) unsigned char smem[65280];
  unsigned short* B1p   = (unsigned short*)smem;
  unsigned short* featp = (unsigned short*)(smem + 21504);
  unsigned short* B2p   = (unsigned short*)(smem + 46848);
  unsigned short* xyzb  = B2p;
  int* lut              = (int*)(smem + 46848 + 6256);

  const int x0 = blockIdx.x * 64;
  const int y  = blockIdx.y;
  const int n  = blockIdx.z;
  const int tid = threadIdx.x;
  const int lane = tid & 63;
  const int wv = tid >> 6;
  const int r16 = lane & 15;
  const int kq = lane >> 4;
  const int wrow = wv & 3, wcol = wv >> 2;
  const int ccb = 16 * wrow + 4 * kq;

  // ---- stage new_xyz as bf16 (rows (c,ki) 0..20, 134 wide, halo 3) ----
  for (int row = wv; row < 21; row += 8) {
    int c = row / 7;           // wave-uniform, 3 iters
    int ki = row - c * 7;
    int yy = y + ki - 3;
    bool rowok = (unsigned)yy < 64u;
    const float* src = new_xyz + ((n * 3 + c) * 64 + yy) * 512;
#pragma unroll
    for (int seg = 0; seg < 3; ++seg) {
      int xx = lane + seg * 64;
      if (xx < 134) {
        int xg = x0 + xx - 3;
        float v = (rowok && (unsigned)xg < 512u) ? src[xg] : 0.f;
        xyzb[row * 136 + xx] = f2bf(v);
      }
    }
  }
  // constant rows for bias/zero K-slots
  if (tid < 136) {
    xyzb[21 * 136 + tid] = 0;        // zeros row (k=148..159)
    xyzb[22 * 136 + tid] = 0x3F80;   // ones row  (k=147 bias slot)
  } else if (tid >= 256 && tid < 416) {
    int k = tid - 256;
    int off;
    if (k < 147) {
      int c = k / 49, rem = k - c * 49, ki = rem / 7, kj = rem - ki * 7;
      off = (c * 7 + ki) * 136 + kj;
    } else if (k == 147) off = 22 * 136;
    else off = 21 * 136;
    lut[k] = off;
  }
  // ---- stage feature tile bf16, swizzled: [r][xx][(c+4*xx)&63] ----
  for (int row = wv; row < 192; row += 8) {   // row = r*64 + c
    int c = row & 63, r = row >> 6;
    int yy = y + r - 1;
    bool rowok = (unsigned)yy < 64u;
    const float* src = feature + ((n * 64 + c) * 64 + yy) * 512;
#pragma unroll
    for (int seg = 0; seg < 2; ++seg) {
      int xx = lane + seg * 64;
      if (xx < 66) {
        int xg = x0 + xx - 1;
        float v = (rowok && (unsigned)xg < 512u) ? src[xg] : 0.f;
        featp[(r * 66 + xx) * 64 + ((c + 4 * xx) & 63)] = f2bf(v);
      }
    }
  }
  __syncthreads();

  // ---- build im2col B1 via LUT: thread (p = tid>>3, q = tid&7), 5 b64 writes ----
  {
    int p = tid >> 3, q = tid & 7;
    unsigned short* brow = B1p + p * 168;
#pragma unroll
    for (int j = 0; j < 5; ++j) {
      int k = (q * 5 + j) * 4;
      int o0 = lut[k], o1 = lut[k + 1], o2 = lut[k + 2], o3 = lut[k + 3];
      uint2 w;
      w.x = (unsigned int)xyzb[o0 + p] | ((unsigned int)xyzb[o1 + p] << 16);
      w.y = (unsigned int)xyzb[o2 + p] | ((unsigned int)xyzb[o3 + p] << 16);
      *(uint2*)(brow + k) = w;
    }
  }
  __syncthreads();

  // bias1 values for this thread's 4 output channels (hoisted)
  float b1v0 = bias1[ccb], b1v1 = bias1[ccb + 1], b1v2 = bias1[ccb + 2], b1v3 = bias1[ccb + 3];

  f32x4 acc2[2];
#pragma unroll
  for (int i = 0; i < 2; ++i) acc2[i] = {0.f, 0.f, 0.f, 0.f};

#pragma unroll
  for (int kk = 0; kk < 9; ++kk) {
    const int di = kk / 3, dj = kk - di * 3;   // compile-time after unroll
    // ---- GEMM1 chunk: 64 rows (kk*64..+64), this wave: 16 rows x 32 px ----
    f32x4 acc1[2];
#pragma unroll
    for (int i = 0; i < 2; ++i) acc1[i] = {0.f, 0.f, 0.f, 0.f};
    const unsigned short* Ap = wAe + (kk * 64 + 16 * wrow + r16) * 160 + kq * 8;
#pragma unroll
    for (int kst = 0; kst < 5; ++kst) {
      bf16x8 a = *(const bf16x8*)(Ap + kst * 32);
#pragma unroll
      for (int pf = 0; pf < 2; ++pf) {
        const unsigned short* bp = B1p + (32 * wcol + 16 * pf + r16) * 168 + kst * 32 + kq * 8;
        acc1[pf] = __builtin_amdgcn_mfma_f32_16x16x32_bf16(a, *(const bf16x8*)bp, acc1[pf], 0, 0, 0);
      }
    }
    // ---- gate: att = sigmoid(acc1); B2[p][cc] = att * feat[cc][di][p+dj] ----
    unsigned short* B2buf = B2p + (kk & 1) * (64 * 72);
#pragma unroll
    for (int pf = 0; pf < 2; ++pf) {
      int p = 32 * wcol + 16 * pf + r16;
      int xxp = p + dj;
      const unsigned short* fp = featp + (di * 66 + xxp) * 64 + ((ccb + 4 * xxp) & 63);
      uint2 fv = *(const uint2*)fp;
      float f0 = bf2f((unsigned short)(fv.x & 0xFFFF));
      float f1 = bf2f((unsigned short)(fv.x >> 16));
      float f2 = bf2f((unsigned short)(fv.y & 0xFFFF));
      float f3 = bf2f((unsigned short)(fv.y >> 16));
      float a0 = sigm(acc1[pf][0]) * f0;
      float a1 = sigm(acc1[pf][1]) * f1;
      float a2 = sigm(acc1[pf][2]) * f2;
      float a3 = sigm(acc1[pf][3]) * f3;
      uint2 w;
      w.x = (unsigned int)f2bf(a0) | ((unsigned int)f2bf(a1) << 16);
      w.y = (unsigned int)f2bf(a2) | ((unsigned int)f2bf(a3) << 16);
      *(uint2*)(B2buf + p * 72 + ccb) = w;
    }
    __syncthreads();
    // ---- GEMM2 partial over this 64-k slice ----
    const unsigned short* A2p = w1e + (16 * wrow + r16) * 576 + kk * 64 + kq * 8;
#pragma unroll
    for (int kst = 0; kst < 2; ++kst) {
      bf16x8 a = *(const bf16x8*)(A2p + kst * 32);
#pragma unroll
      for (int pf = 0; pf < 2; ++pf) {
        const unsigned short* bp = B2buf + (32 * wcol + 16 * pf + r16) * 72 + kst * 32 + kq * 8;
        acc2[pf] = __builtin_amdgcn_mfma_f32_16x16x32_bf16(a, *(const bf16x8*)bp, acc2[pf], 0, 0, 0);
      }
    }
  }

  // ---- epilogue: h1 = relu(acc2 + bias1) -> bf16 via buf1 transpose ----
  unsigned short* sT = B2p + 64 * 72;   // buf1: last read finished before barrier in kk=8
#pragma unroll
  for (int pf = 0; pf < 2; ++pf) {
    int p = 32 * wcol + 16 * pf + r16;
    uint2 w;
    w.x = (unsigned int)f2bf(fmaxf(acc2[pf][0] + b1v0, 0.f)) |
          ((unsigned int)f2bf(fmaxf(acc2[pf][1] + b1v1, 0.f)) << 16);
    w.y = (unsigned int)f2bf(fmaxf(acc2[pf][2] + b1v2, 0.f)) |
          ((unsigned int)f2bf(fmaxf(acc2[pf][3] + b1v3, 0.f)) << 16);
    *(uint2*)(sT + p * 72 + ccb) = w;
  }
  __syncthreads();
  {
    int p = tid >> 3, c0 = (tid & 7) * 8;
    uint4 v = *(const uint4*)(sT + p * 72 + c0);
    *(uint4*)(h1g + (((n * 64 + y) * 512) + x0) * 64 + p * 64 + c0) = v;
  }
}

// ---------------- K3: 3x3 conv 64->64 + BN + ReLU + residual ----------------
__global__ __launch_bounds__(256) void k3_kernel(
    const unsigned short* __restrict__ h1g, const float* __restrict__ feature,
    const unsigned short* __restrict__ w2e, const float* __restrict__ bias2,
    float* __restrict__ out)
{
  __shared__ unsigned short s_h1[3][66][72];  // [row][xx][c], stride 144B

  const int x0 = blockIdx.x * 64;
  const int y  = blockIdx.y;
  const int n  = blockIdx.z;
  const int tid = threadIdx.x;
  const int lane = tid & 63;
  const int wv = tid >> 6;
  const int r16 = lane & 15;
  const int kq = lane >> 4;

  for (int idx = tid; idx < 3 * 66 * 16; idx += 256) {
    int r = idx / (66 * 16), rem = idx - r * 66 * 16, xx = rem >> 4, c0 = (rem & 15) << 2;
    int yy = y + r - 1, xg = x0 + xx - 1;
    uint2 v; v.x = 0u; v.y = 0u;
    if (yy >= 0 && yy < 64 && xg >= 0 && xg < 512)
      v = *(const uint2*)(h1g + (((n * 64 + yy) * 512) + xg) * 64 + c0);
    *(uint2*)(&s_h1[r][xx][c0]) = v;
  }
  __syncthreads();

  f32x4 acc[4];
#pragma unroll
  for (int i = 0; i < 4; ++i) acc[i] = {0.f, 0.f, 0.f, 0.f};

  const unsigned short* Ap = w2e + (16 * wv + r16) * 576 + kq * 8;
#pragma unroll 2
  for (int kst = 0; kst < 18; ++kst) {
    bf16x8 a = *(const bf16x8*)(Ap + kst * 32);
    int kk = kst >> 1, di = kk / 3, dj = kk - di * 3;
    int chalf = (kst & 1) << 5;
#pragma unroll
    for (int pf = 0; pf < 4; ++pf) {
      bf16x8 b = *(const bf16x8*)(&s_h1[di][pf * 16 + r16 + dj][chalf + kq * 8]);
      acc[pf] = __builtin_amdgcn_mfma_f32_16x16x32_bf16(a, b, acc[pf], 0, 0, 0);
    }
  }

#pragma unroll
  for (int pf = 0; pf < 4; ++pf) {
    int p = pf * 16 + r16;
#pragma unroll
    for (int r = 0; r < 4; ++r) {
      int ch = 16 * wv + kq * 4 + r;
      int off = (((n * 64 + ch) * 64) + y) * 512 + x0 + p;
      out[off] = fmaxf(acc[pf][r] + bias2[ch], 0.f) + feature[off];
    }
  }
}

// ---------------- launch ----------------
extern "C" void kernel_launch(void* const* d_in, const int* in_sizes, int n_in,
                              void* d_out, int out_size, void* d_ws, size_t ws_size,
                              hipStream_t stream)
{
  const float* new_xyz = (const float*)d_in[1];
  const float* feature = (const float*)d_in[2];
  const float* w_att = (const float*)d_in[3];
  const float* b_att = (const float*)d_in[4];
  const float* gA  = (const float*)d_in[5];
  const float* beA = (const float*)d_in[6];
  const float* mA  = (const float*)d_in[7];
  const float* vA  = (const float*)d_in[8];
  const float* w1  = (const float*)d_in[9];
  const float* b1  = (const float*)d_in[10];
  const float* g1  = (const float*)d_in[11];
  const float* be1 = (const float*)d_in[12];
  const float* m1  = (const float*)d_in[13];
  const float* v1  = (const float*)d_in[14];
  const float* w2  = (const float*)d_in[15];
  const float* b2  = (const float*)d_in[16];
  const float* g2  = (const float*)d_in[17];
  const float* be2 = (const float*)d_in[18];
  const float* m2  = (const float*)d_in[19];
  const float* v2  = (const float*)d_in[20];

  char* ws = (char*)d_ws;
  unsigned short* wAe = (unsigned short*)(ws);             // 576*160*2 = 184320
  unsigned short* w1e = (unsigned short*)(ws + 184320);    // 64*576*2  =  73728
  unsigned short* w2e = (unsigned short*)(ws + 258048);    // 64*576*2  =  73728
  float* bias1 = (float*)(ws + 331776);                    // 256
  float* bias2 = (float*)(ws + 332032);                    // 256
  unsigned short* h1g = (unsigned short*)(ws + 335872);    // 4*64*512*64*2 = 16777216

  prep_kernel<<<649, 256, 0, stream>>>(w_att, b_att, gA, beA, mA, vA,
                                       w1, b1, g1, be1, m1, v1,
                                       w2, b2, g2, be2, m2, v2,
                                       wAe, w1e, w2e, bias1, bias2);
  k12_kernel<<<dim3(8, 64, 4), 512, 0, stream>>>(new_xyz, feature, wAe, w1e, bias1, h1g);
  k3_kernel<<<dim3(8, 64, 4), 256, 0, stream>>>(h1g, feature, w2e, bias2, (float*)d_out);
}